// Round 4
// baseline (137.618 us; speedup 1.0000x reference)
//
#include <hip/hip_runtime.h>

#define T0 4096
#define N1 2051          // level-1 output length
#define BLOCK 256
#define PAD 6            // left pad; right pad is 7

// filters reversed so tap k multiplies ext[2i+k]  (rLO[k] = DEC_LO[7-k])
#define RLO0  0.23037781330885523f
#define RLO1  0.7148465705525415f
#define RLO2  0.6308807679295904f
#define RLO3 -0.02798376941698385f
#define RLO4 -0.18703481171888114f
#define RLO5  0.030841381835986965f
#define RLO6  0.032883011666982945f
#define RLO7 -0.010597401784997278f

#define RHI0 -0.010597401784997278f
#define RHI1 -0.032883011666982945f
#define RHI2  0.030841381835986965f
#define RHI3  0.18703481171888114f
#define RHI4 -0.02798376941698385f
#define RHI5 -0.6308807679295904f
#define RHI6  0.7148465705525415f
#define RHI7 -0.23037781330885523f

__device__ __forceinline__ int symidx(int t, int L) {
    t = (t < 0) ? (-1 - t) : t;
    t = (t >= L) ? (2 * L - 1 - t) : t;
    return t;
}

__device__ __forceinline__ void filt8(const float* __restrict__ t,
                                      float& lo, float& hi) {
    lo = RLO0 * t[0];            hi = RHI0 * t[0];
    lo = fmaf(RLO1, t[1], lo);   hi = fmaf(RHI1, t[1], hi);
    lo = fmaf(RLO2, t[2], lo);   hi = fmaf(RHI2, t[2], hi);
    lo = fmaf(RLO3, t[3], lo);   hi = fmaf(RHI3, t[3], hi);
    lo = fmaf(RLO4, t[4], lo);   hi = fmaf(RHI4, t[4], hi);
    lo = fmaf(RLO5, t[5], lo);   hi = fmaf(RHI5, t[5], hi);
    lo = fmaf(RLO6, t[6], lo);   hi = fmaf(RHI6, t[6], hi);
    lo = fmaf(RLO7, t[7], lo);   hi = fmaf(RHI7, t[7], hi);
}

__global__ __launch_bounds__(BLOCK) void dwt5_kernel(
    const float* __restrict__ x, float* __restrict__ out,
    long long offA, long long offD1, long long offD2, long long offD3,
    long long offD4, long long offD5)
{
    __shared__ float extB[N1 + 16];    // level-1 approx, padded
    __shared__ float extC[1029 + 16];  // ping-pong for levels 2..5

    const int row = blockIdx.x;
    const int tid = threadIdx.x;
    const float* __restrict__ xrow = x + (size_t)row * T0;
    float* __restrict__ d1 = out + offD1 + (long long)row * N1;

    // ---- level 1: two register-resident passes, 4 outputs/thread ----
    const int iA = 4 * tid;          // pass A outputs iA..iA+3   (0..1023)
    const int iB = 1024 + 4 * tid;   // pass B outputs iB..iB+3   (1024..2047)
    const bool fastA = (tid != 0);   // t=0 needs left reflection

    float2 a[7], b[7];
    if (fastA) {
        const float2* __restrict__ pA =
            reinterpret_cast<const float2*>(xrow + 2 * iA - 6);
#pragma unroll
        for (int k = 0; k < 7; ++k) a[k] = pA[k];
    }
    {
        const float2* __restrict__ pB =
            reinterpret_cast<const float2*>(xrow + 2 * iB - 6);
#pragma unroll
        for (int k = 0; k < 7; ++k) b[k] = pB[k];
    }

    if (fastA) {
        float t[14];
#pragma unroll
        for (int k = 0; k < 7; ++k) { t[2 * k] = a[k].x; t[2 * k + 1] = a[k].y; }
#pragma unroll
        for (int j = 0; j < 4; ++j) {
            float lo, hi;
            filt8(t + 2 * j, lo, hi);
            const int i = iA + j;
            __builtin_nontemporal_store(hi, &d1[i]);
            extB[PAD + i] = lo;
            if (i < 6) extB[5 - i] = lo;          // left mirror (i=4,5)
        }
    } else {
        // thread 0: outputs 0..3 with reflected taps
#pragma unroll
        for (int j = 0; j < 4; ++j) {
            float t[8];
#pragma unroll
            for (int k = 0; k < 8; ++k) t[k] = xrow[symidx(2 * j - 6 + k, T0)];
            float lo, hi;
            filt8(t, lo, hi);
            __builtin_nontemporal_store(hi, &d1[j]);
            extB[PAD + j] = lo;
            extB[5 - j] = lo;                     // left mirror (j<6 always)
        }
    }
    {
        float t[14];
#pragma unroll
        for (int k = 0; k < 7; ++k) { t[2 * k] = b[k].x; t[2 * k + 1] = b[k].y; }
#pragma unroll
        for (int j = 0; j < 4; ++j) {
            float lo, hi;
            filt8(t + 2 * j, lo, hi);
            const int i = iB + j;
            __builtin_nontemporal_store(hi, &d1[i]);
            extB[PAD + i] = lo;
            if (i >= N1 - 7) extB[PAD + N1 + (N1 - 1 - i)] = lo;  // right mirror
        }
    }
    if (tid < 3) {                   // tail outputs 2048..2050
        const int i = 2048 + tid;
        float t[8];
#pragma unroll
        for (int k = 0; k < 8; ++k) t[k] = xrow[symidx(2 * i - 6 + k, T0)];
        float lo, hi;
        filt8(t, lo, hi);
        __builtin_nontemporal_store(hi, &d1[i]);
        extB[PAD + i] = lo;
        extB[PAD + N1 + (N1 - 1 - i)] = lo;       // right mirror (i>=2044)
    }
    __syncthreads();

    // ---- levels 2..5 from LDS (stride-1-per-lane: conflict-free) ----
    const long long dOff[4] = {offD2, offD3, offD4, offD5};
    float* src = extB;
    float* dst = extC;
    int L = N1;
#pragma unroll
    for (int lev = 0; lev < 4; ++lev) {
        const int nOut = (L + 7) >> 1;
        float* __restrict__ dSeg = out + dOff[lev] + (long long)row * nOut;
        float* __restrict__ aSeg = out + offA + (long long)row * nOut;
        const float2* __restrict__ e2 = reinterpret_cast<const float2*>(src);
        for (int i = tid; i < nOut; i += BLOCK) {
            const float2 w0 = e2[i + 0];
            const float2 w1 = e2[i + 1];
            const float2 w2 = e2[i + 2];
            const float2 w3 = e2[i + 3];
            const float t[8] = {w0.x, w0.y, w1.x, w1.y, w2.x, w2.y, w3.x, w3.y};
            float lo, hi;
            filt8(t, lo, hi);
            __builtin_nontemporal_store(hi, &dSeg[i]);
            if (lev == 3) {
                __builtin_nontemporal_store(lo, &aSeg[i]);
            } else {
                dst[PAD + i] = lo;
                if (i < 6)         dst[5 - i] = lo;
                if (i >= nOut - 7) dst[PAD + nOut + (nOut - 1 - i)] = lo;
            }
        }
        __syncthreads();
        float* tmp = src; src = dst; dst = tmp;
        L = nOut;
    }
}

extern "C" void kernel_launch(void* const* d_in, const int* in_sizes, int n_in,
                              void* d_out, int out_size, void* d_ws, size_t ws_size,
                              hipStream_t stream) {
    const float* x = (const float*)d_in[0];
    float* out = (float*)d_out;

    const int rows = in_sizes[0] / T0;   // 64*64 = 4096
    const int n1 = (T0 + 7) / 2;         // 2051
    const int n2 = (n1 + 7) / 2;         // 1029
    const int n3 = (n2 + 7) / 2;         // 518
    const int n4 = (n3 + 7) / 2;         // 262
    const int n5 = (n4 + 7) / 2;         // 134

    const long long offA  = 0;
    const long long offD5 = offA  + (long long)rows * n5;
    const long long offD4 = offD5 + (long long)rows * n5;
    const long long offD3 = offD4 + (long long)rows * n4;
    const long long offD2 = offD3 + (long long)rows * n3;
    const long long offD1 = offD2 + (long long)rows * n2;

    dwt5_kernel<<<rows, BLOCK, 0, stream>>>(x, out, offA, offD1, offD2, offD3,
                                            offD4, offD5);
}

// Round 5
// 111.455 us; speedup vs baseline: 1.2347x; 1.2347x over previous
//
#include <hip/hip_runtime.h>

#define T0 4096
#define N1 2051          // level-1 output length
#define BLOCK 256
#define PAD 6            // left pad; right pad is 7

// filters reversed so tap k multiplies ext[2i+k]  (rLO[k] = DEC_LO[7-k])
#define RLO0  0.23037781330885523f
#define RLO1  0.7148465705525415f
#define RLO2  0.6308807679295904f
#define RLO3 -0.02798376941698385f
#define RLO4 -0.18703481171888114f
#define RLO5  0.030841381835986965f
#define RLO6  0.032883011666982945f
#define RLO7 -0.010597401784997278f

#define RHI0 -0.010597401784997278f
#define RHI1 -0.032883011666982945f
#define RHI2  0.030841381835986965f
#define RHI3  0.18703481171888114f
#define RHI4 -0.02798376941698385f
#define RHI5 -0.6308807679295904f
#define RHI6  0.7148465705525415f
#define RHI7 -0.23037781330885523f

__device__ __forceinline__ int symidx(int t, int L) {
    t = (t < 0) ? (-1 - t) : t;
    t = (t >= L) ? (2 * L - 1 - t) : t;
    return t;
}

__device__ __forceinline__ void filt8(const float* __restrict__ t,
                                      float& lo, float& hi) {
    lo = RLO0 * t[0];            hi = RHI0 * t[0];
    lo = fmaf(RLO1, t[1], lo);   hi = fmaf(RHI1, t[1], hi);
    lo = fmaf(RLO2, t[2], lo);   hi = fmaf(RHI2, t[2], hi);
    lo = fmaf(RLO3, t[3], lo);   hi = fmaf(RHI3, t[3], hi);
    lo = fmaf(RLO4, t[4], lo);   hi = fmaf(RHI4, t[4], hi);
    lo = fmaf(RLO5, t[5], lo);   hi = fmaf(RHI5, t[5], hi);
    lo = fmaf(RLO6, t[6], lo);   hi = fmaf(RHI6, t[6], hi);
    lo = fmaf(RLO7, t[7], lo);   hi = fmaf(RHI7, t[7], hi);
}

__global__ __launch_bounds__(BLOCK) void dwt5_kernel(
    const float* __restrict__ x, float* __restrict__ out,
    long long offA, long long offD1, long long offD2, long long offD3,
    long long offD4, long long offD5)
{
    __shared__ float extB[N1 + 16];    // level-1 approx, padded
    __shared__ float extC[1029 + 16];  // ping-pong for levels 2..5

    const int row = blockIdx.x;
    const int tid = threadIdx.x;
    const float* __restrict__ xrow = x + (size_t)row * T0;
    float* __restrict__ d1 = out + offD1 + (long long)row * N1;

    // ---- level 1: 8 lane-consecutive outputs/thread (i = tid + 256k),
    // ALL 32 float2 tap loads issued up front for deep in-flight reads ----
    float2 t[8][4];
    {
        // k=0: lanes 0..2 would read xrow[-6..]; clamp (fixed up below)
        const int b0 = (tid >= 3) ? (2 * tid - 6) : 0;
        const float2* __restrict__ p = reinterpret_cast<const float2*>(xrow + b0);
#pragma unroll
        for (int q = 0; q < 4; ++q) t[0][q] = p[q];
    }
#pragma unroll
    for (int k = 1; k < 8; ++k) {
        const float2* __restrict__ p =
            reinterpret_cast<const float2*>(xrow + 2 * (tid + 256 * k) - 6);
#pragma unroll
        for (int q = 0; q < 4; ++q) t[k][q] = p[q];
    }

#pragma unroll
    for (int k = 0; k < 8; ++k) {
        const int i = tid + 256 * k;            // 0..2047
        const float tt[8] = {t[k][0].x, t[k][0].y, t[k][1].x, t[k][1].y,
                             t[k][2].x, t[k][2].y, t[k][3].x, t[k][3].y};
        float lo, hi;
        filt8(tt, lo, hi);
        __builtin_nontemporal_store(hi, &d1[i]);
        extB[PAD + i] = lo;
        if (i < 6)       extB[5 - i] = lo;                    // left mirror
        if (i >= N1 - 7) extB[PAD + N1 + (N1 - 1 - i)] = lo;  // right mirror (2044..2047)
    }

    // fix-ups: outputs 0..2 (overwrite clamped garbage) and tail 2048..2050
    if (tid < 3) {
        {
            const int i = tid;
            float tt[8];
#pragma unroll
            for (int k = 0; k < 8; ++k) tt[k] = xrow[symidx(2 * i - 6 + k, T0)];
            float lo, hi;
            filt8(tt, lo, hi);
            __builtin_nontemporal_store(hi, &d1[i]);
            extB[PAD + i] = lo;
            extB[5 - i] = lo;                                 // left mirror
        }
        {
            const int i = 2048 + tid;
            float tt[8];
#pragma unroll
            for (int k = 0; k < 8; ++k) tt[k] = xrow[symidx(2 * i - 6 + k, T0)];
            float lo, hi;
            filt8(tt, lo, hi);
            __builtin_nontemporal_store(hi, &d1[i]);
            extB[PAD + i] = lo;
            extB[PAD + N1 + (N1 - 1 - i)] = lo;               // right mirror
        }
    }
    __syncthreads();

    // ---- levels 2..5 from LDS (lane-consecutive: conflict-free, coalesced) ----
    const long long dOff[4] = {offD2, offD3, offD4, offD5};
    float* src = extB;
    float* dst = extC;
    int L = N1;
#pragma unroll
    for (int lev = 0; lev < 4; ++lev) {
        const int nOut = (L + 7) >> 1;
        float* __restrict__ dSeg = out + dOff[lev] + (long long)row * nOut;
        float* __restrict__ aSeg = out + offA + (long long)row * nOut;
        const float2* __restrict__ e2 = reinterpret_cast<const float2*>(src);
        for (int i = tid; i < nOut; i += BLOCK) {
            const float2 w0 = e2[i + 0];
            const float2 w1 = e2[i + 1];
            const float2 w2 = e2[i + 2];
            const float2 w3 = e2[i + 3];
            const float tt[8] = {w0.x, w0.y, w1.x, w1.y, w2.x, w2.y, w3.x, w3.y};
            float lo, hi;
            filt8(tt, lo, hi);
            __builtin_nontemporal_store(hi, &dSeg[i]);
            if (lev == 3) {
                __builtin_nontemporal_store(lo, &aSeg[i]);
            } else {
                dst[PAD + i] = lo;
                if (i < 6)         dst[5 - i] = lo;
                if (i >= nOut - 7) dst[PAD + nOut + (nOut - 1 - i)] = lo;
            }
        }
        __syncthreads();
        float* tmp = src; src = dst; dst = tmp;
        L = nOut;
    }
}

extern "C" void kernel_launch(void* const* d_in, const int* in_sizes, int n_in,
                              void* d_out, int out_size, void* d_ws, size_t ws_size,
                              hipStream_t stream) {
    const float* x = (const float*)d_in[0];
    float* out = (float*)d_out;

    const int rows = in_sizes[0] / T0;   // 64*64 = 4096
    const int n1 = (T0 + 7) / 2;         // 2051
    const int n2 = (n1 + 7) / 2;         // 1029
    const int n3 = (n2 + 7) / 2;         // 518
    const int n4 = (n3 + 7) / 2;         // 262
    const int n5 = (n4 + 7) / 2;         // 134

    const long long offA  = 0;
    const long long offD5 = offA  + (long long)rows * n5;
    const long long offD4 = offD5 + (long long)rows * n5;
    const long long offD3 = offD4 + (long long)rows * n4;
    const long long offD2 = offD3 + (long long)rows * n3;
    const long long offD1 = offD2 + (long long)rows * n2;

    dwt5_kernel<<<rows, BLOCK, 0, stream>>>(x, out, offA, offD1, offD2, offD3,
                                            offD4, offD5);
}